// Round 2
// baseline (720.002 us; speedup 1.0000x reference)
//
#include <hip/hip_runtime.h>
#include <math.h>

#define NTOK   65536
#define MDIM   1024
#define NE     64     // experts
#define TT     64     // tokens per block
#define TW     16     // tokens per wave
#define MC     64     // M chunk staged in LDS (W only)
#define WPAD   65

// Output layout (flat f32, reference return order):
//   gates[NTOK*NE] | H[NTOK*NE] | topk_idx[NTOK*2] | noise_scale[NTOK*NE] | logits[NTOK*NE]

__global__ __launch_bounds__(256, 4) void noisy_topk_gate_kernel(
    const float* __restrict__ x,      // [NTOK][MDIM]
    const float* __restrict__ noise,  // [NTOK][NE]
    const float* __restrict__ Wg_w,   // [NE][MDIM]
    const float* __restrict__ Wg_b,   // [NE]
    const float* __restrict__ Wn_w,   // [NE][MDIM]
    const float* __restrict__ Wn_b,   // [NE]
    float* __restrict__ out_gates,
    float* __restrict__ out_H,
    float* __restrict__ out_idx,
    float* __restrict__ out_ns,
    float* __restrict__ out_logits)
{
    // W chunks transposed: [m][expert] -> lane reads its expert column, conflict-free b32
    __shared__ float wgs[MC][WPAD];
    __shared__ float wns[MC][WPAD];

    const int tid  = threadIdx.x;
    const int lane = tid & 63;                                   // expert index
    const int wave = __builtin_amdgcn_readfirstlane(tid >> 6);   // force wave-uniform
    const int tok0 = blockIdx.x * TT;

    // wave-uniform x base pointer -> scalar (s_load) path for x
    const float* __restrict__ xw = x + (size_t)(tok0 + wave * TW) * MDIM;

    float accg[TW], accn[TW];
#pragma unroll
    for (int j = 0; j < TW; ++j) { accg[j] = 0.f; accn[j] = 0.f; }

    for (int mc = 0; mc < MDIM; mc += MC) {
        if (mc != 0) __syncthreads();

        // stage W chunks transposed: 64 e x 64 m, 4 float4 per thread per matrix
#pragma unroll
        for (int k = 0; k < 4; ++k) {
            const int f  = tid + k * 256;
            const int e  = f >> 4;          // 16 float4 per W row chunk
            const int mq = f & 15;
            const float4 vg = *reinterpret_cast<const float4*>(
                &Wg_w[(size_t)e * MDIM + mc + mq * 4]);
            const float4 vn = *reinterpret_cast<const float4*>(
                &Wn_w[(size_t)e * MDIM + mc + mq * 4]);
            wgs[mq * 4 + 0][e] = vg.x; wgs[mq * 4 + 1][e] = vg.y;
            wgs[mq * 4 + 2][e] = vg.z; wgs[mq * 4 + 3][e] = vg.w;
            wns[mq * 4 + 0][e] = vn.x; wns[mq * 4 + 1][e] = vn.y;
            wns[mq * 4 + 2][e] = vn.z; wns[mq * 4 + 3][e] = vn.w;
        }
        __syncthreads();

        // compute: lane = expert; x comes in via SGPRs (uniform loads)
#pragma unroll 4
        for (int m = 0; m < MC; m += 4) {
            const float wg0 = wgs[m + 0][lane];
            const float wg1 = wgs[m + 1][lane];
            const float wg2 = wgs[m + 2][lane];
            const float wg3 = wgs[m + 3][lane];
            const float wn0 = wns[m + 0][lane];
            const float wn1 = wns[m + 1][lane];
            const float wn2 = wns[m + 2][lane];
            const float wn3 = wns[m + 3][lane];
#pragma unroll
            for (int j = 0; j < TW; ++j) {
                const float4 xv = *reinterpret_cast<const float4*>(
                    &xw[(size_t)j * MDIM + mc + m]);    // uniform -> s_load_dwordx4
                float ag = accg[j], an = accn[j];
                ag = fmaf(xv.x, wg0, ag);
                ag = fmaf(xv.y, wg1, ag);
                ag = fmaf(xv.z, wg2, ag);
                ag = fmaf(xv.w, wg3, ag);
                an = fmaf(xv.x, wn0, an);
                an = fmaf(xv.y, wn1, an);
                an = fmaf(xv.z, wn2, an);
                an = fmaf(xv.w, wn3, an);
                accg[j] = ag; accn[j] = an;
            }
        }
    }

    // ---- epilogue
    const float bg = Wg_b[lane];
    const float bn = Wn_b[lane];

#pragma unroll
    for (int j = 0; j < TW; ++j) {
        const int tok = tok0 + wave * TW + j;
        const float lg = accg[j] + bg;
        const float nl = accn[j] + bn;
        // softplus, stable: max(x,0) + log1p(exp(-|x|))
        const float ns = fmaxf(nl, 0.f) + log1pf(expf(-fabsf(nl)));
        const float nz = noise[(size_t)tok * NE + lane];
        const float h  = fmaf(nz, ns, lg);

        out_logits[(size_t)tok * NE + lane] = lg;
        out_ns[(size_t)tok * NE + lane]     = ns;
        out_H[(size_t)tok * NE + lane]      = h;

        // top-1 (value, lowest index on ties)
        float v1 = h; int i1 = lane;
#pragma unroll
        for (int off = 32; off >= 1; off >>= 1) {
            const float ov = __shfl_xor(v1, off, 64);
            const int   oi = __shfl_xor(i1, off, 64);
            if (ov > v1 || (ov == v1 && oi < i1)) { v1 = ov; i1 = oi; }
        }
        // top-2: exclude argmax lane
        float v2 = (lane == i1) ? -INFINITY : h; int i2 = lane;
#pragma unroll
        for (int off = 32; off >= 1; off >>= 1) {
            const float ov = __shfl_xor(v2, off, 64);
            const int   oi = __shfl_xor(i2, off, 64);
            if (ov > v2 || (ov == v2 && oi < i2)) { v2 = ov; i2 = oi; }
        }

        // softmax over [v1, v2] (v1 >= v2)
        const float e2  = expf(v2 - v1);
        const float inv = 1.f / (1.f + e2);
        const float p1  = inv;
        const float p2  = e2 * inv;

        out_gates[(size_t)tok * NE + lane] =
            (lane == i1) ? p1 : ((lane == i2) ? p2 : 0.f);

        if (lane == 0) {
            out_idx[(size_t)tok * 2 + 0] = (float)i1;
            out_idx[(size_t)tok * 2 + 1] = (float)i2;
        }
    }
}

extern "C" void kernel_launch(void* const* d_in, const int* in_sizes, int n_in,
                              void* d_out, int out_size, void* d_ws, size_t ws_size,
                              hipStream_t stream) {
    const float* x     = (const float*)d_in[0];
    const float* noise = (const float*)d_in[1];
    const float* Wg_w  = (const float*)d_in[2];
    const float* Wg_b  = (const float*)d_in[3];
    const float* Wn_w  = (const float*)d_in[4];
    const float* Wn_b  = (const float*)d_in[5];

    float* out = (float*)d_out;
    float* out_gates  = out;
    float* out_H      = out + (size_t)NTOK * NE;
    float* out_idx    = out + (size_t)2 * NTOK * NE;
    float* out_ns     = out + (size_t)2 * NTOK * NE + (size_t)NTOK * 2;
    float* out_logits = out + (size_t)3 * NTOK * NE + (size_t)NTOK * 2;

    dim3 grid(NTOK / TT);   // 1024 blocks
    dim3 block(256);
    noisy_topk_gate_kernel<<<grid, block, 0, stream>>>(
        x, noise, Wg_w, Wg_b, Wn_w, Wn_b,
        out_gates, out_H, out_idx, out_ns, out_logits);
}

// Round 3
// 464.186 us; speedup vs baseline: 1.5511x; 1.5511x over previous
//
#include <hip/hip_runtime.h>
#include <math.h>

#define NTOK 65536
#define MDIM 1024
#define NE   64     // experts
#define TB   128    // tokens per block
#define TWV  32     // tokens per wave
#define MC   32     // M chunk in LDS
#define XP   36     // x row pad (floats): 144B rows, stride%32=4 -> conflict-free
#define WP   36     // W row pad

// Output layout (flat f32, reference return order):
//   gates[NTOK*NE] | H[NTOK*NE] | topk_idx[NTOK*2] | noise_scale[NTOK*NE] | logits[NTOK*NE]

__global__ __launch_bounds__(256, 4) void noisy_topk_gate_kernel(
    const float* __restrict__ x,      // [NTOK][MDIM]
    const float* __restrict__ noise,  // [NTOK][NE]
    const float* __restrict__ Wg_w,   // [NE][MDIM]
    const float* __restrict__ Wg_b,   // [NE]
    const float* __restrict__ Wn_w,   // [NE][MDIM]
    const float* __restrict__ Wn_b,   // [NE]
    float* __restrict__ out_gates,
    float* __restrict__ out_H,
    float* __restrict__ out_idx,
    float* __restrict__ out_ns,
    float* __restrict__ out_logits)
{
    __shared__ float xs[TB][XP];     // [token][m]
    __shared__ float wgs[NE][WP];    // [expert][m] (natural layout)
    __shared__ float wns[NE][WP];

    const int tid  = threadIdx.x;
    const int lane = tid & 63;
    const int wave = tid >> 6;
    const int tr   = lane >> 3;   // token-row within wave tile
    const int er   = lane & 7;    // expert-col group
    const int tok0 = blockIdx.x * TB;

    // per-lane tile: tokens {wave*32 + 8j + tr, j=0..3} x experts {er + 8e, e=0..7}
    float accg[4][8], accn[4][8];
#pragma unroll
    for (int j = 0; j < 4; ++j)
#pragma unroll
        for (int e = 0; e < 8; ++e) { accg[j][e] = 0.f; accn[j][e] = 0.f; }

    for (int mc = 0; mc < MDIM; mc += MC) {
        if (mc != 0) __syncthreads();

        // ---- stage x: 128 rows x 8 float4 = 1024 float4, 4/thread
#pragma unroll
        for (int k = 0; k < 4; ++k) {
            const int f   = tid + k * 256;
            const int row = f >> 3;
            const int mq  = f & 7;
            const float4 v = *reinterpret_cast<const float4*>(
                &x[(size_t)(tok0 + row) * MDIM + mc + mq * 4]);
            *reinterpret_cast<float4*>(&xs[row][mq * 4]) = v;
        }
        // ---- stage W (both matrices, natural [e][m] layout): 512 float4 each
#pragma unroll
        for (int k = 0; k < 2; ++k) {
            const int f  = tid + k * 256;
            const int e  = f >> 3;
            const int mq = f & 7;
            const float4 vg = *reinterpret_cast<const float4*>(
                &Wg_w[(size_t)e * MDIM + mc + mq * 4]);
            const float4 vn = *reinterpret_cast<const float4*>(
                &Wn_w[(size_t)e * MDIM + mc + mq * 4]);
            *reinterpret_cast<float4*>(&wgs[e][mq * 4]) = vg;
            *reinterpret_cast<float4*>(&wns[e][mq * 4]) = vn;
        }
        __syncthreads();

        // ---- compute: 20 b128 LDS reads per 256 FMAs
#pragma unroll
        for (int m = 0; m < MC; m += 4) {
            float4 xv[4];
#pragma unroll
            for (int j = 0; j < 4; ++j)
                xv[j] = *reinterpret_cast<const float4*>(
                    &xs[wave * TWV + 8 * j + tr][m]);

#pragma unroll
            for (int eh = 0; eh < 2; ++eh) {   // split e-range to cap live W regs
                float4 wg[4], wn[4];
#pragma unroll
                for (int e = 0; e < 4; ++e) {
                    wg[e] = *reinterpret_cast<const float4*>(
                        &wgs[er + 8 * (eh * 4 + e)][m]);
                    wn[e] = *reinterpret_cast<const float4*>(
                        &wns[er + 8 * (eh * 4 + e)][m]);
                }
#pragma unroll
                for (int j = 0; j < 4; ++j)
#pragma unroll
                    for (int e = 0; e < 4; ++e) {
                        const int ei = eh * 4 + e;
                        float ag = accg[j][ei];
                        ag = fmaf(xv[j].x, wg[e].x, ag);
                        ag = fmaf(xv[j].y, wg[e].y, ag);
                        ag = fmaf(xv[j].z, wg[e].z, ag);
                        ag = fmaf(xv[j].w, wg[e].w, ag);
                        accg[j][ei] = ag;
                        float an = accn[j][ei];
                        an = fmaf(xv[j].x, wn[e].x, an);
                        an = fmaf(xv[j].y, wn[e].y, an);
                        an = fmaf(xv[j].z, wn[e].z, an);
                        an = fmaf(xv[j].w, wn[e].w, an);
                        accn[j][ei] = an;
                    }
            }
        }
    }

    // ---- epilogue
    float bg[8], bn[8];
#pragma unroll
    for (int e = 0; e < 8; ++e) {
        bg[e] = Wg_b[er + 8 * e];
        bn[e] = Wn_b[er + 8 * e];
    }

#pragma unroll
    for (int j = 0; j < 4; ++j) {
        const int tok = tok0 + wave * TWV + 8 * j + tr;

        float v1 = -INFINITY, v2 = -INFINITY;
        int   i1 = 0,         i2 = 0;
        float hv[8];
#pragma unroll
        for (int e = 0; e < 8; ++e) {
            const int ex = er + 8 * e;
            const float lg = accg[j][e] + bg[e];
            const float nl = accn[j][e] + bn[e];
            const float ns = fmaxf(nl, 0.f) + log1pf(expf(-fabsf(nl)));
            const float nz = noise[(size_t)tok * NE + ex];
            const float h  = fmaf(nz, ns, lg);
            hv[e] = h;
            out_logits[(size_t)tok * NE + ex] = lg;
            out_ns[(size_t)tok * NE + ex]     = ns;
            out_H[(size_t)tok * NE + ex]      = h;
            // in-lane top-2 scan, ascending index => strict > keeps lowest idx on tie
            if (h > v1)      { v2 = v1; i2 = i1; v1 = h; i1 = ex; }
            else if (h > v2) { v2 = h;  i2 = ex; }
        }

        // merge across the 8 er-lanes (offsets 1,2,4 stay within the group)
#pragma unroll
        for (int off = 1; off <= 4; off <<= 1) {
            const float w1 = __shfl_xor(v1, off, 64);
            const int   k1 = __shfl_xor(i1, off, 64);
            const float w2 = __shfl_xor(v2, off, 64);
            const int   k2 = __shfl_xor(i2, off, 64);
            if (w1 > v1 || (w1 == v1 && k1 < i1)) {
                // w1 becomes top1; new top2 = better of (v1,i1) vs (w2,k2)
                if (v1 > w2 || (v1 == w2 && i1 < k2)) { v2 = v1; i2 = i1; }
                else                                  { v2 = w2; i2 = k2; }
                v1 = w1; i1 = k1;
            } else {
                if (w1 > v2 || (w1 == v2 && k1 < i2)) { v2 = w1; i2 = k1; }
            }
        }

        const float e2  = expf(v2 - v1);
        const float inv = 1.f / (1.f + e2);
        const float p1  = inv;
        const float p2  = e2 * inv;

#pragma unroll
        for (int e = 0; e < 8; ++e) {
            const int ex = er + 8 * e;
            out_gates[(size_t)tok * NE + ex] =
                (ex == i1) ? p1 : ((ex == i2) ? p2 : 0.f);
        }
        if (er == 0) {
            out_idx[(size_t)tok * 2 + 0] = (float)i1;
            out_idx[(size_t)tok * 2 + 1] = (float)i2;
        }
    }
}

extern "C" void kernel_launch(void* const* d_in, const int* in_sizes, int n_in,
                              void* d_out, int out_size, void* d_ws, size_t ws_size,
                              hipStream_t stream) {
    const float* x     = (const float*)d_in[0];
    const float* noise = (const float*)d_in[1];
    const float* Wg_w  = (const float*)d_in[2];
    const float* Wg_b  = (const float*)d_in[3];
    const float* Wn_w  = (const float*)d_in[4];
    const float* Wn_b  = (const float*)d_in[5];

    float* out = (float*)d_out;
    float* out_gates  = out;
    float* out_H      = out + (size_t)NTOK * NE;
    float* out_idx    = out + (size_t)2 * NTOK * NE;
    float* out_ns     = out + (size_t)2 * NTOK * NE + (size_t)NTOK * 2;
    float* out_logits = out + (size_t)3 * NTOK * NE + (size_t)NTOK * 2;

    dim3 grid(NTOK / TB);   // 512 blocks
    dim3 block(256);
    noisy_topk_gate_kernel<<<grid, block, 0, stream>>>(
        x, noise, Wg_w, Wg_b, Wn_w, Wn_b,
        out_gates, out_H, out_idx, out_ns, out_logits);
}

// Round 4
// 290.704 us; speedup vs baseline: 2.4768x; 1.5968x over previous
//
#include <hip/hip_runtime.h>
#include <math.h>

#define NTOK 65536
#define MDIM 1024
#define NE   64     // experts
#define TB   128    // tokens per block
#define MC   32     // M chunk in LDS
#define XP   36     // x row pad: 144B rows (16B-aligned), tr spread conflict-free
#define WTP  68     // w^T row pad: 272B rows (16B-aligned)

// float4 component by (unrolled-literal) index
#define F4C(v, i) ((i) == 0 ? (v).x : (i) == 1 ? (v).y : (i) == 2 ? (v).z : (v).w)

// Output layout (flat f32, reference return order):
//   gates[NTOK*NE] | H[NTOK*NE] | topk_idx[NTOK*2] | noise_scale[NTOK*NE] | logits[NTOK*NE]

__global__ __launch_bounds__(256, 3) void noisy_topk_gate_kernel(
    const float* __restrict__ x,      // [NTOK][MDIM]
    const float* __restrict__ noise,  // [NTOK][NE]
    const float* __restrict__ Wg_w,   // [NE][MDIM]
    const float* __restrict__ Wg_b,   // [NE]
    const float* __restrict__ Wn_w,   // [NE][MDIM]
    const float* __restrict__ Wn_b,   // [NE]
    float* __restrict__ out_gates,
    float* __restrict__ out_H,
    float* __restrict__ out_idx,
    float* __restrict__ out_ns,
    float* __restrict__ out_logits)
{
    __shared__ float xs[TB][XP];    // [token][m]
    __shared__ float wgt[MC][WTP];  // [m][expert] transposed
    __shared__ float wnt[MC][WTP];

    const int tid  = threadIdx.x;
    const int lane = tid & 63;
    const int wave = tid >> 6;
    const int tr   = lane >> 3;   // token-row in wave tile (8 consecutive tokens)
    const int er   = lane & 7;    // expert block: owns experts [er*8, er*8+8)
    const int ex0  = er * 8;
    const int tok0 = blockIdx.x * TB;

    // per-lane tile: tokens {wave*32 + 8j + tr}, experts {ex0..ex0+7}, 2 matrices
    float accg[4][8], accn[4][8];
#pragma unroll
    for (int j = 0; j < 4; ++j)
#pragma unroll
        for (int e = 0; e < 8; ++e) { accg[j][e] = 0.f; accn[j][e] = 0.f; }

    for (int mc = 0; mc < MDIM; mc += MC) {
        if (mc != 0) __syncthreads();

        // ---- stage x: 128 rows x 8 float4 = 1024 float4, 4/thread
#pragma unroll
        for (int k = 0; k < 4; ++k) {
            const int f   = tid + k * 256;
            const int row = f >> 3;
            const int q   = f & 7;
            const float4 v = *reinterpret_cast<const float4*>(
                &x[(size_t)(tok0 + row) * MDIM + mc + q * 4]);
            *reinterpret_cast<float4*>(&xs[row][q * 4]) = v;
        }
        // ---- stage W transposed: 64e x 32m per matrix = 512 float4, 2/thread
#pragma unroll
        for (int k = 0; k < 2; ++k) {
            const int f = tid + k * 256;
            const int e = f >> 3;
            const int q = f & 7;
            const float4 vg = *reinterpret_cast<const float4*>(
                &Wg_w[(size_t)e * MDIM + mc + q * 4]);
            const float4 vn = *reinterpret_cast<const float4*>(
                &Wn_w[(size_t)e * MDIM + mc + q * 4]);
#pragma unroll
            for (int i = 0; i < 4; ++i) {
                wgt[q * 4 + i][e] = F4C(vg, i);
                wnt[q * 4 + i][e] = F4C(vn, i);
            }
        }
        __syncthreads();

        // ---- compute: per 4-m: 4 x-b128 + 16 w-b128 per 256 FMAs
#pragma unroll
        for (int m4 = 0; m4 < MC; m4 += 4) {
            float4 xv[4];
#pragma unroll
            for (int j = 0; j < 4; ++j)
                xv[j] = *reinterpret_cast<const float4*>(
                    &xs[wave * 32 + 8 * j + tr][m4]);

#pragma unroll
            for (int mi = 0; mi < 4; ++mi) {
                const int m = m4 + mi;
                const float4 wgl = *reinterpret_cast<const float4*>(&wgt[m][ex0]);
                const float4 wgh = *reinterpret_cast<const float4*>(&wgt[m][ex0 + 4]);
                const float4 wnl = *reinterpret_cast<const float4*>(&wnt[m][ex0]);
                const float4 wnh = *reinterpret_cast<const float4*>(&wnt[m][ex0 + 4]);
#pragma unroll
                for (int j = 0; j < 4; ++j) {
                    const float xm = F4C(xv[j], mi);
#pragma unroll
                    for (int e = 0; e < 4; ++e) {
                        accg[j][e]     = fmaf(xm, F4C(wgl, e), accg[j][e]);
                        accg[j][e + 4] = fmaf(xm, F4C(wgh, e), accg[j][e + 4]);
                        accn[j][e]     = fmaf(xm, F4C(wnl, e), accn[j][e]);
                        accn[j][e + 4] = fmaf(xm, F4C(wnh, e), accn[j][e + 4]);
                    }
                }
            }
        }
    }

    // ---- epilogue: contiguous 8 experts/lane -> all global IO as float4
    const float4 bgl = *reinterpret_cast<const float4*>(&Wg_b[ex0]);
    const float4 bgh = *reinterpret_cast<const float4*>(&Wg_b[ex0 + 4]);
    const float4 bnl = *reinterpret_cast<const float4*>(&Wn_b[ex0]);
    const float4 bnh = *reinterpret_cast<const float4*>(&Wn_b[ex0 + 4]);

#pragma unroll
    for (int j = 0; j < 4; ++j) {
        const int tok = tok0 + wave * 32 + 8 * j + tr;
        const size_t rb = (size_t)tok * NE + ex0;

        const float4 nzl = *reinterpret_cast<const float4*>(&noise[rb]);
        const float4 nzh = *reinterpret_cast<const float4*>(&noise[rb + 4]);

        float lg[8], nsv[8], h[8];
#pragma unroll
        for (int e = 0; e < 4; ++e) {
            lg[e]     = accg[j][e]     + F4C(bgl, e);
            lg[e + 4] = accg[j][e + 4] + F4C(bgh, e);
            const float nl0 = accn[j][e]     + F4C(bnl, e);
            const float nl1 = accn[j][e + 4] + F4C(bnh, e);
            nsv[e]     = fmaxf(nl0, 0.f) + log1pf(expf(-fabsf(nl0)));
            nsv[e + 4] = fmaxf(nl1, 0.f) + log1pf(expf(-fabsf(nl1)));
            h[e]     = fmaf(F4C(nzl, e), nsv[e],     lg[e]);
            h[e + 4] = fmaf(F4C(nzh, e), nsv[e + 4], lg[e + 4]);
        }

        *reinterpret_cast<float4*>(&out_logits[rb])     = make_float4(lg[0], lg[1], lg[2], lg[3]);
        *reinterpret_cast<float4*>(&out_logits[rb + 4]) = make_float4(lg[4], lg[5], lg[6], lg[7]);
        *reinterpret_cast<float4*>(&out_ns[rb])         = make_float4(nsv[0], nsv[1], nsv[2], nsv[3]);
        *reinterpret_cast<float4*>(&out_ns[rb + 4])     = make_float4(nsv[4], nsv[5], nsv[6], nsv[7]);
        *reinterpret_cast<float4*>(&out_H[rb])          = make_float4(h[0], h[1], h[2], h[3]);
        *reinterpret_cast<float4*>(&out_H[rb + 4])      = make_float4(h[4], h[5], h[6], h[7]);

        // in-lane top-2 over 8 contiguous experts (ascending idx, strict > keeps lowest)
        float v1 = -INFINITY, v2 = -INFINITY;
        int   i1 = 0,         i2 = 0;
#pragma unroll
        for (int e = 0; e < 8; ++e) {
            const int ex = ex0 + e;
            if (h[e] > v1)      { v2 = v1; i2 = i1; v1 = h[e]; i1 = ex; }
            else if (h[e] > v2) { v2 = h[e]; i2 = ex; }
        }
        // merge across 8 er-lanes (offsets 1,2,4; tr unchanged)
#pragma unroll
        for (int off = 1; off <= 4; off <<= 1) {
            const float w1 = __shfl_xor(v1, off, 64);
            const int   k1 = __shfl_xor(i1, off, 64);
            const float w2 = __shfl_xor(v2, off, 64);
            const int   k2 = __shfl_xor(i2, off, 64);
            if (w1 > v1 || (w1 == v1 && k1 < i1)) {
                if (v1 > w2 || (v1 == w2 && i1 < k2)) { v2 = v1; i2 = i1; }
                else                                  { v2 = w2; i2 = k2; }
                v1 = w1; i1 = k1;
            } else {
                if (w1 > v2 || (w1 == v2 && k1 < i2)) { v2 = w1; i2 = k1; }
            }
        }

        const float e2v = expf(v2 - v1);
        const float inv = 1.f / (1.f + e2v);
        const float p1  = inv;
        const float p2  = e2v * inv;

        float g[8];
#pragma unroll
        for (int e = 0; e < 8; ++e) {
            const int ex = ex0 + e;
            g[e] = (ex == i1) ? p1 : ((ex == i2) ? p2 : 0.f);
        }
        *reinterpret_cast<float4*>(&out_gates[rb])     = make_float4(g[0], g[1], g[2], g[3]);
        *reinterpret_cast<float4*>(&out_gates[rb + 4]) = make_float4(g[4], g[5], g[6], g[7]);

        if (er == 0) {
            *reinterpret_cast<float2*>(&out_idx[(size_t)tok * 2]) =
                make_float2((float)i1, (float)i2);
        }
    }
}

extern "C" void kernel_launch(void* const* d_in, const int* in_sizes, int n_in,
                              void* d_out, int out_size, void* d_ws, size_t ws_size,
                              hipStream_t stream) {
    const float* x     = (const float*)d_in[0];
    const float* noise = (const float*)d_in[1];
    const float* Wg_w  = (const float*)d_in[2];
    const float* Wg_b  = (const float*)d_in[3];
    const float* Wn_w  = (const float*)d_in[4];
    const float* Wn_b  = (const float*)d_in[5];

    float* out = (float*)d_out;
    float* out_gates  = out;
    float* out_H      = out + (size_t)NTOK * NE;
    float* out_idx    = out + (size_t)2 * NTOK * NE;
    float* out_ns     = out + (size_t)2 * NTOK * NE + (size_t)NTOK * 2;
    float* out_logits = out + (size_t)3 * NTOK * NE + (size_t)NTOK * 2;

    dim3 grid(NTOK / TB);   // 512 blocks
    dim3 block(256);
    noisy_topk_gate_kernel<<<grid, block, 0, stream>>>(
        x, noise, Wg_w, Wg_b, Wn_w, Wn_b,
        out_gates, out_H, out_idx, out_ns, out_logits);
}